// Round 9
// baseline (824.034 us; speedup 1.0000x reference)
//
#include <hip/hip_runtime.h>

typedef float f32x4  __attribute__((ext_vector_type(4)));
typedef float f32x16 __attribute__((ext_vector_type(16)));
typedef int   i32x4  __attribute__((ext_vector_type(4)));
typedef int   i32x8  __attribute__((ext_vector_type(8)));

#define AS1 __attribute__((address_space(1)))
#define AS3 __attribute__((address_space(3)))

// ---------------------------------------------------------------------------
// Kernel 1 (R1, proven): per-token quant of x -> fp8 e4m3 + scale
// ---------------------------------------------------------------------------
__global__ __launch_bounds__(256) void quant_x_fp8_kernel(
    const float* __restrict__ x, unsigned char* __restrict__ x8,
    float* __restrict__ xs, int K) {
  int m = blockIdx.x;
  int t = threadIdx.x;
  const f32x4* src = (const f32x4*)(x + (size_t)m * K + t * 16);
  f32x4 v[4];
  float am = 0.0f;
#pragma unroll
  for (int i = 0; i < 4; ++i) {
    v[i] = src[i];
#pragma unroll
    for (int j = 0; j < 4; ++j) am = fmaxf(am, __builtin_fabsf(v[i][j]));
  }
#pragma unroll
  for (int off = 32; off >= 1; off >>= 1)
    am = fmaxf(am, __shfl_xor(am, off, 64));
  __shared__ float red[4];
  int wv = t >> 6, lane = t & 63;
  if (lane == 0) red[wv] = am;
  __syncthreads();
  am = fmaxf(fmaxf(red[0], red[1]), fmaxf(red[2], red[3]));
  am = fmaxf(am, 1e-12f);
  float sc = am / 448.0f;
  if (t == 0) xs[m] = sc;
  i32x4 out;
#pragma unroll
  for (int i = 0; i < 4; ++i) {
    float q0 = v[i][0] / sc, q1 = v[i][1] / sc;
    float q2 = v[i][2] / sc, q3 = v[i][3] / sc;
    int p = __builtin_amdgcn_cvt_pk_fp8_f32(q0, q1, 0, false);
    p = __builtin_amdgcn_cvt_pk_fp8_f32(q2, q3, p, true);
    out[i] = p;
  }
  *(i32x4*)(x8 + (size_t)m * K + t * 16) = out;
}

// ---------------------------------------------------------------------------
// Kernel 2 (R1, proven): weight f32 (fp8-representable) -> fp8 bytes
// ---------------------------------------------------------------------------
__global__ __launch_bounds__(256) void quant_w_fp8_kernel(
    const float* __restrict__ w, unsigned char* __restrict__ w8) {
  size_t idx = (size_t)blockIdx.x * 256 + threadIdx.x;
  const f32x4* src = (const f32x4*)w + idx * 4;
  i32x4 out;
#pragma unroll
  for (int i = 0; i < 4; ++i) {
    f32x4 v = src[i];
    int p = __builtin_amdgcn_cvt_pk_fp8_f32(v[0], v[1], 0, false);
    p = __builtin_amdgcn_cvt_pk_fp8_f32(v[2], v[3], p, true);
    out[i] = p;
  }
  ((i32x4*)w8)[idx] = out;
}

// ---------------------------------------------------------------------------
// Kernel 3: MX-fp8 GEMM. R21 = R20 body at 2 blocks/CU (80KB LDS).
// R20 post-mortem: 169us, MfmaUtil 36.5, no spill. Cycle audit: 3170cy/tile
// vs LDS 1920 + MFMA 1100 + VALU ~600 -> pipes still mostly serial. At 1
// block/CU the 2 waves/SIMD are phase-locked (identical program, same
// barrier) so LDS and MFMA alternate idle. m97's overlap mechanism is
// CO-RESIDENT BLOCKS (independent, no shared barrier) -> anti-phased stalls.
// R21: LDS = A0@0 A1@32768 (2x32KB, double-buf) + B@65536 (16KB, SINGLE
// buf) = 81920 B exactly -> 2 blocks/CU (2x80KB = 160KB), 4 waves/SIMD.
// B single-buffer discipline: all 8 B reads of tile T retire before each
// wave's first MFMA (in-order lgkm); explicit lgkmcnt(0) (+memory clobber,
// LDS reads cannot sink past it) + mid-body barrier -> block-wide retire;
// then STG_B(T+1) overwrites safely with ~400cy in-body cover; residual
// latency absorbed by the co-resident block. A: stage(T+1) at body top into
// buf of T-1 (reads drained 1 barrier earlier, R17/R20 rule) - full-body
// cover. vmcnt(0) before closing barrier (A:4 + B:2 outstanding, both
// needed next body). launch_bounds(512,4) pins allocator at 128 VGPR
// (R20 body = 96, fits; tripwire: WRITE_SIZE must stay exactly 131072KB).
// Fold (R20-validated): acc *= s_prev/s_cur in place; MFMA C-chains into
// acc; epilogue * s_last. Geometry: 256(M)x128(N), K-tile 128, 8 waves
// 4(wr)x2(wc), wave 64x64, acc[2][2] f32x16.
// Swizzle (validated): 16B slot s at row r stored s^(r&7); inverse applied
// on global source (rule #21).
// ---------------------------------------------------------------------------
__global__ __launch_bounds__(512, 4) void gemm_mxfp8_kernel(
    const unsigned char* __restrict__ A8,   // [M][K] fp8
    const unsigned char* __restrict__ W8,   // [N][K] fp8
    const float* __restrict__ xs,           // [M]
    const float* __restrict__ wsinv,        // [N/128][K/128]
    float* __restrict__ Y,                  // [M][N] f32
    int M, int N, int K) {
  const int KB = K >> 7;  // K/128 tiles (32)

  int bid = blockIdx.x, nwg = gridDim.x;
  int wg = (bid & 7) * (nwg >> 3) + (bid >> 3);
  int mt = M >> 8;                  // 16
  int bm = wg & (mt - 1);
  int bn = wg / mt;
  int m0 = bm << 8, n0 = bn << 7;   // 256 x 128 tile

  __shared__ __align__(16) char lds[81920];  // A0@0 A1@32768 B@65536

  const int tid = threadIdx.x, wv = tid >> 6, lane = tid & 63;
  const int wr = wv >> 1, wc = wv & 1;          // 4 x 2 wave grid
  const int l31 = lane & 31, hi2 = lane >> 5;
  const int salt = l31 & 7;

  // per-lane slot offsets (validated swizzle)
  const int sL0 = ((hi2 * 2 + 0) ^ salt) << 4;       // ks=0, k-low 16B
  const int sH0 = ((hi2 * 2 + 1) ^ salt) << 4;       // ks=0, k-high
  const int sL1 = ((4 + hi2 * 2 + 0) ^ salt) << 4;   // ks=1
  const int sH1 = ((4 + hi2 * 2 + 1) ^ salt) << 4;

  // shared per-lane anchors (region base added at runtime)
  const int aRow = (wr * 64 + l31) * 128;
  const int bRow = (wc * 64 + l31) * 128;
  const int aL0 = aRow + sL0, aH0 = aRow + sH0;
  const int aL1 = aRow + sL1, aH1 = aRow + sH1;
  const int bL0 = bRow + sL0, bH0 = bRow + sH0;
  const int bL1 = bRow + sL1, bH1 = bRow + sH1;

  // staging: dest = region + sweep*8192 + tid*16 (linear, 64 rows/sweep);
  // source row = sweep*64 + (tid>>3); col pre-swizzled (involution).
  const int stgD = tid << 4;
  const int rIdx = tid >> 3;
  const int cSrc = ((tid & 7) ^ ((tid >> 3) & 7)) << 4;
  const size_t rowB = (size_t)K;  // fp8: 1 byte/elem
  const size_t g64 = 64 * rowB;
  const char* pA = (const char*)A8 + (size_t)(m0 + rIdx) * rowB + cSrc;
  const char* pB = (const char*)W8 + (size_t)(n0 + rIdx) * rowB + cSrc;

  const float* wsv = wsinv + (size_t)bn * KB;  // block-uniform scale row

  f32x16 acc[2][2];
#pragma unroll
  for (int i = 0; i < 2; ++i)
#pragma unroll
    for (int j = 0; j < 2; ++j) acc[i][j] = (f32x16)0.0f;

  i32x8 af[2], bf[2][2];

#define GL(SRC, DST)                                                           \
  __builtin_amdgcn_global_load_lds((const AS1 void*)(SRC), (AS3 void*)(DST),   \
                                   16, 0, 0)
#define STG_A(COND, SB, SRC)                                                   \
  if (COND) {                                                                  \
    const char* s_ = (SRC);                                                    \
    char* d_ = lds + (SB) + stgD;                                              \
    GL(s_, d_);                                                                \
    GL(s_ + g64, d_ + 8192);                                                   \
    GL(s_ + 2 * g64, d_ + 16384);                                              \
    GL(s_ + 3 * g64, d_ + 24576);                                              \
  }
#define STG_B(COND, SB, SRC)                                                   \
  if (COND) {                                                                  \
    const char* s_ = (SRC);                                                    \
    char* d_ = lds + (SB) + stgD;                                              \
    GL(s_, d_);                                                                \
    GL(s_ + g64, d_ + 8192);                                                   \
  }

// A frags for one mj (both ksteps), runtime region base RB: 4 ds_read_b128
#define RD_A(RB, MJ)                                                           \
  {                                                                            \
    const char* p_ = lds + (RB) + (MJ) * 4096;                                 \
    i32x4 lo0 = *(const i32x4*)(p_ + aL0);                                     \
    i32x4 hi0 = *(const i32x4*)(p_ + aH0);                                     \
    i32x4 lo1 = *(const i32x4*)(p_ + aL1);                                     \
    i32x4 hi1 = *(const i32x4*)(p_ + aH1);                                     \
    af[0] = __builtin_shufflevector(lo0, hi0, 0, 1, 2, 3, 4, 5, 6, 7);         \
    af[1] = __builtin_shufflevector(lo1, hi1, 0, 1, 2, 3, 4, 5, 6, 7);         \
  }
// all B frags (nj 0..1 x ks 0..1) from literal base BR: 8 ds_read_b128
#define RD_B(BR)                                                               \
  _Pragma("unroll") for (int nj = 0; nj < 2; ++nj) {                           \
    const char* p_ = lds + (BR) + nj * 4096;                                   \
    i32x4 lo0 = *(const i32x4*)(p_ + bL0);                                     \
    i32x4 hi0 = *(const i32x4*)(p_ + bH0);                                     \
    i32x4 lo1 = *(const i32x4*)(p_ + bL1);                                     \
    i32x4 hi1 = *(const i32x4*)(p_ + bH1);                                     \
    bf[nj][0] = __builtin_shufflevector(lo0, hi0, 0, 1, 2, 3, 4, 5, 6, 7);     \
    bf[nj][1] = __builtin_shufflevector(lo1, hi1, 0, 1, 2, 3, 4, 5, 6, 7);     \
  }

// ratio-fold + chained MFMA pair for one (mj,nj); acc touched only by the
// in-place mul and as MFMA C/D (R20-validated numerics).
#define MMFn(MJ, NJ, R_)                                                       \
  {                                                                            \
    _Pragma("unroll") for (int q = 0; q < 16; ++q)                             \
        acc[MJ][NJ][q] *= (R_);                                                \
    acc[MJ][NJ] = __builtin_amdgcn_mfma_scale_f32_32x32x64_f8f6f4(             \
        af[0], bf[NJ][0], acc[MJ][NJ], 0, 0, 0, 0x7f7f7f7f, 0, 0x7f7f7f7f);    \
    acc[MJ][NJ] = __builtin_amdgcn_mfma_scale_f32_32x32x64_f8f6f4(             \
        af[1], bf[NJ][1], acc[MJ][NJ], 0, 0, 0, 0x7f7f7f7f, 0, 0x7f7f7f7f);    \
  }

  // prologue: A(0)->A0, B(0)->B (6 gloads); drain; publish.
  STG_A(true, 0, pA);
  STG_B(true, 65536, pB);
  asm volatile("s_waitcnt vmcnt(0)" ::: "memory");
  __builtin_amdgcn_s_barrier();

  int rdA = 0, stA = 32768;    // A double-buffer swap
  const char* pAs = pA + 128;  // stage source col of tile T+1
  const char* pBs = pB + 128;
  float sp_ = wsv[0];          // previous-tile scale (ratio = 1 at t = 0)

// body T: stage A(T+1) at top (full-body cover); after first MFMA chunk all
// ds reads are retired in-wave (in-order lgkm); explicit lgkmcnt(0) +
// barrier makes that block-wide -> STG_B(T+1) into the single B buf is
// race-free with ~400cy cover; vmcnt(0)+barrier close (A:4+B:2 outstanding,
// both read next body).
#define TILE(T, G)                                                             \
  {                                                                            \
    float sc_ = wsv[(T)];                                                      \
    float r_ = sp_ / sc_;                                                      \
    RD_B(65536);                                                               \
    RD_A(rdA, 0);                                                              \
    STG_A(G, stA, pAs);                                                        \
    __builtin_amdgcn_s_setprio(1);                                             \
    MMFn(0, 0, r_);                                                            \
    __builtin_amdgcn_s_setprio(0);                                             \
    asm volatile("s_waitcnt lgkmcnt(0)" ::: "memory");                         \
    __builtin_amdgcn_s_barrier();                                              \
    STG_B(G, 65536, pBs);                                                      \
    __builtin_amdgcn_s_setprio(1);                                             \
    MMFn(0, 1, r_);                                                            \
    __builtin_amdgcn_s_setprio(0);                                             \
    RD_A(rdA, 1);                                                              \
    __builtin_amdgcn_s_setprio(1);                                             \
    MMFn(1, 0, r_);                                                            \
    MMFn(1, 1, r_);                                                            \
    __builtin_amdgcn_s_setprio(0);                                             \
    sp_ = sc_;                                                                 \
    asm volatile("s_waitcnt vmcnt(0)" ::: "memory");                           \
    __builtin_amdgcn_s_barrier();                                              \
    rdA ^= 32768;                                                              \
    stA ^= 32768;                                                              \
    pAs += 128;                                                                \
    pBs += 128;                                                                \
  }

#pragma unroll 1
  for (int t = 0; t < KB - 1; ++t) {
    TILE(t, true)
  }
  // last tile: no staging.
  TILE(KB - 1, false)

#undef TILE
#undef MMFn
#undef RD_B
#undef RD_A
#undef STG_B
#undef STG_A
#undef GL

  // epilogue (validated C/D mapping): col=l31, row=q*8+hi2*4+j.
  // acc is in s_last domain: Y = acc * s_last * xs[row].
  const float sl_ = sp_;
#pragma unroll
  for (int mj = 0; mj < 2; ++mj)
#pragma unroll
    for (int nj = 0; nj < 2; ++nj) {
      int col = n0 + wc * 64 + nj * 32 + l31;
#pragma unroll
      for (int q = 0; q < 4; ++q) {
        int row0 = m0 + wr * 64 + mj * 32 + q * 8 + hi2 * 4;
        f32x4 sv = *(const f32x4*)(xs + row0);
#pragma unroll
        for (int j = 0; j < 4; ++j)
          Y[(size_t)(row0 + j) * N + col] = acc[mj][nj][q * 4 + j] * sv[j] * sl_;
      }
    }
}

// ---------------------------------------------------------------------------
extern "C" void kernel_launch(void* const* d_in, const int* in_sizes, int n_in,
                              void* d_out, int out_size, void* d_ws, size_t ws_size,
                              hipStream_t stream) {
  const float* x     = (const float*)d_in[0];   // [B,S,K] f32
  const float* w     = (const float*)d_in[1];   // [N,K] f32 (fp8-representable)
  const float* wsinv = (const float*)d_in[2];   // [N/128,K/128] f32
  float* y = (float*)d_out;

  const int K = 4096;
  const int M = in_sizes[0] / K;   // 4096
  const int N = in_sizes[1] / K;   // 8192

  unsigned char* x8 = (unsigned char*)d_ws;                       // M*K
  float* xs = (float*)((char*)d_ws + (size_t)M * K);              // M floats
  unsigned char* w8 =
      (unsigned char*)d_ws + (size_t)M * K + (size_t)M * 4;       // N*K

  quant_x_fp8_kernel<<<M, 256, 0, stream>>>(x, x8, xs, K);
  quant_w_fp8_kernel<<<(int)(((size_t)N * K / 16 + 255) / 256), 256, 0,
                       stream>>>(w, w8);

  dim3 grid((M / 256) * (N / 128));  // 1024
  gemm_mxfp8_kernel<<<grid, 512, 0, stream>>>(x8, w8, xs, wsinv, y, M, N, K);
}

// Round 10
// 238.880 us; speedup vs baseline: 3.4496x; 3.4496x over previous
//
#include <hip/hip_runtime.h>

typedef float f32x4  __attribute__((ext_vector_type(4)));
typedef float f32x16 __attribute__((ext_vector_type(16)));
typedef int   i32x4  __attribute__((ext_vector_type(4)));
typedef int   i32x8  __attribute__((ext_vector_type(8)));

#define AS1 __attribute__((address_space(1)))
#define AS3 __attribute__((address_space(3)))

// ---------------------------------------------------------------------------
// Kernel 1 (R1, proven): per-token quant of x -> fp8 e4m3 + scale
// ---------------------------------------------------------------------------
__global__ __launch_bounds__(256) void quant_x_fp8_kernel(
    const float* __restrict__ x, unsigned char* __restrict__ x8,
    float* __restrict__ xs, int K) {
  int m = blockIdx.x;
  int t = threadIdx.x;
  const f32x4* src = (const f32x4*)(x + (size_t)m * K + t * 16);
  f32x4 v[4];
  float am = 0.0f;
#pragma unroll
  for (int i = 0; i < 4; ++i) {
    v[i] = src[i];
#pragma unroll
    for (int j = 0; j < 4; ++j) am = fmaxf(am, __builtin_fabsf(v[i][j]));
  }
#pragma unroll
  for (int off = 32; off >= 1; off >>= 1)
    am = fmaxf(am, __shfl_xor(am, off, 64));
  __shared__ float red[4];
  int wv = t >> 6, lane = t & 63;
  if (lane == 0) red[wv] = am;
  __syncthreads();
  am = fmaxf(fmaxf(red[0], red[1]), fmaxf(red[2], red[3]));
  am = fmaxf(am, 1e-12f);
  float sc = am / 448.0f;
  if (t == 0) xs[m] = sc;
  i32x4 out;
#pragma unroll
  for (int i = 0; i < 4; ++i) {
    float q0 = v[i][0] / sc, q1 = v[i][1] / sc;
    float q2 = v[i][2] / sc, q3 = v[i][3] / sc;
    int p = __builtin_amdgcn_cvt_pk_fp8_f32(q0, q1, 0, false);
    p = __builtin_amdgcn_cvt_pk_fp8_f32(q2, q3, p, true);
    out[i] = p;
  }
  *(i32x4*)(x8 + (size_t)m * K + t * 16) = out;
}

// ---------------------------------------------------------------------------
// Kernel 2 (R1, proven): weight f32 (fp8-representable) -> fp8 bytes
// ---------------------------------------------------------------------------
__global__ __launch_bounds__(256) void quant_w_fp8_kernel(
    const float* __restrict__ w, unsigned char* __restrict__ w8) {
  size_t idx = (size_t)blockIdx.x * 256 + threadIdx.x;
  const f32x4* src = (const f32x4*)w + idx * 4;
  i32x4 out;
#pragma unroll
  for (int i = 0; i < 4; ++i) {
    f32x4 v = src[i];
    int p = __builtin_amdgcn_cvt_pk_fp8_f32(v[0], v[1], 0, false);
    p = __builtin_amdgcn_cvt_pk_fp8_f32(v[2], v[3], p, true);
    out[i] = p;
  }
  ((i32x4*)w8)[idx] = out;
}

// ---------------------------------------------------------------------------
// Kernel 3: MX-fp8 GEMM. R22 = R21 schedule with __launch_bounds__(512, 1).
// R21 post-mortem: the (512,4) attribute made the allocator budget 64
// VGPR/wave -> spill (VGPR 64, WRITE 2.04GB scratch). Allocator law
// (4 confirmations): cap = 512/min-waves-requested, stepped 64/128/256;
// (512,1)/(512,2) -> 128, (512,4) -> 64, 1024-thread -> 64. The R21
// SCHEDULE passed (absmax 0.0625) -> single-B-buf + 80KB layout validated.
// R22: (512,1) -> cap 128; body needs ~96 (R20-measured). 96 <= 128 means
// HW can co-schedule 4 waves/SIMD = 2 blocks/CU anyway (launch_bounds arg
// is an allocator guarantee, not an occupancy ceiling); LDS 81920 x 2 =
// 163840 = exactly the 160KB pool. Two INDEPENDENT blocks per CU
// anti-phase their LDS/MFMA/staging stalls (m97's overlap mechanism,
// which barrier-free scheduling inside one block could never buy).
// LDS: A0@0 A1@32768 (double-buf) + B@65536 (16KB, single buf) = 81920.
// B single-buffer discipline: all 8 B reads of tile T retire before each
// wave's first MFMA (in-order lgkm); explicit lgkmcnt(0) (+memory clobber)
// + mid-body barrier -> block-wide retire; then STG_B(T+1) overwrites
// safely; residual latency absorbed by the co-resident block. A:
// stage(T+1) at body top into buf of T-1 (reads drained 1 barrier earlier,
// R17/R20 rule) - full-body cover. vmcnt(0) before closing barrier.
// Fold (R20-validated): acc *= s_prev/s_cur in place; MFMA C-chains into
// acc; epilogue * s_last. Geometry: 256(M)x128(N), K-tile 128, 8 waves
// 4(wr)x2(wc), wave 64x64, acc[2][2] f32x16.
// Swizzle (validated): 16B slot s at row r stored s^(r&7); inverse applied
// on global source (rule #21).
// Tripwires: VGPR ~96 (64 => allocator choked); WRITE_SIZE == 131072KB
// (else spill); OccupancyPercent ~44 (22 => LDS didn't double-book).
// ---------------------------------------------------------------------------
__global__ __launch_bounds__(512, 1) void gemm_mxfp8_kernel(
    const unsigned char* __restrict__ A8,   // [M][K] fp8
    const unsigned char* __restrict__ W8,   // [N][K] fp8
    const float* __restrict__ xs,           // [M]
    const float* __restrict__ wsinv,        // [N/128][K/128]
    float* __restrict__ Y,                  // [M][N] f32
    int M, int N, int K) {
  const int KB = K >> 7;  // K/128 tiles (32)

  int bid = blockIdx.x, nwg = gridDim.x;
  int wg = (bid & 7) * (nwg >> 3) + (bid >> 3);
  int mt = M >> 8;                  // 16
  int bm = wg & (mt - 1);
  int bn = wg / mt;
  int m0 = bm << 8, n0 = bn << 7;   // 256 x 128 tile

  __shared__ __align__(16) char lds[81920];  // A0@0 A1@32768 B@65536

  const int tid = threadIdx.x, wv = tid >> 6, lane = tid & 63;
  const int wr = wv >> 1, wc = wv & 1;          // 4 x 2 wave grid
  const int l31 = lane & 31, hi2 = lane >> 5;
  const int salt = l31 & 7;

  // per-lane slot offsets (validated swizzle)
  const int sL0 = ((hi2 * 2 + 0) ^ salt) << 4;       // ks=0, k-low 16B
  const int sH0 = ((hi2 * 2 + 1) ^ salt) << 4;       // ks=0, k-high
  const int sL1 = ((4 + hi2 * 2 + 0) ^ salt) << 4;   // ks=1
  const int sH1 = ((4 + hi2 * 2 + 1) ^ salt) << 4;

  // shared per-lane anchors (region base added at runtime)
  const int aRow = (wr * 64 + l31) * 128;
  const int bRow = (wc * 64 + l31) * 128;
  const int aL0 = aRow + sL0, aH0 = aRow + sH0;
  const int aL1 = aRow + sL1, aH1 = aRow + sH1;
  const int bL0 = bRow + sL0, bH0 = bRow + sH0;
  const int bL1 = bRow + sL1, bH1 = bRow + sH1;

  // staging: dest = region + sweep*8192 + tid*16 (linear, 64 rows/sweep);
  // source row = sweep*64 + (tid>>3); col pre-swizzled (involution).
  const int stgD = tid << 4;
  const int rIdx = tid >> 3;
  const int cSrc = ((tid & 7) ^ ((tid >> 3) & 7)) << 4;
  const size_t rowB = (size_t)K;  // fp8: 1 byte/elem
  const size_t g64 = 64 * rowB;
  const char* pA = (const char*)A8 + (size_t)(m0 + rIdx) * rowB + cSrc;
  const char* pB = (const char*)W8 + (size_t)(n0 + rIdx) * rowB + cSrc;

  const float* wsv = wsinv + (size_t)bn * KB;  // block-uniform scale row

  f32x16 acc[2][2];
#pragma unroll
  for (int i = 0; i < 2; ++i)
#pragma unroll
    for (int j = 0; j < 2; ++j) acc[i][j] = (f32x16)0.0f;

  i32x8 af[2], bf[2][2];

#define GL(SRC, DST)                                                           \
  __builtin_amdgcn_global_load_lds((const AS1 void*)(SRC), (AS3 void*)(DST),   \
                                   16, 0, 0)
#define STG_A(COND, SB, SRC)                                                   \
  if (COND) {                                                                  \
    const char* s_ = (SRC);                                                    \
    char* d_ = lds + (SB) + stgD;                                              \
    GL(s_, d_);                                                                \
    GL(s_ + g64, d_ + 8192);                                                   \
    GL(s_ + 2 * g64, d_ + 16384);                                              \
    GL(s_ + 3 * g64, d_ + 24576);                                              \
  }
#define STG_B(COND, SB, SRC)                                                   \
  if (COND) {                                                                  \
    const char* s_ = (SRC);                                                    \
    char* d_ = lds + (SB) + stgD;                                              \
    GL(s_, d_);                                                                \
    GL(s_ + g64, d_ + 8192);                                                   \
  }

// A frags for one mj (both ksteps), runtime region base RB: 4 ds_read_b128
#define RD_A(RB, MJ)                                                           \
  {                                                                            \
    const char* p_ = lds + (RB) + (MJ) * 4096;                                 \
    i32x4 lo0 = *(const i32x4*)(p_ + aL0);                                     \
    i32x4 hi0 = *(const i32x4*)(p_ + aH0);                                     \
    i32x4 lo1 = *(const i32x4*)(p_ + aL1);                                     \
    i32x4 hi1 = *(const i32x4*)(p_ + aH1);                                     \
    af[0] = __builtin_shufflevector(lo0, hi0, 0, 1, 2, 3, 4, 5, 6, 7);         \
    af[1] = __builtin_shufflevector(lo1, hi1, 0, 1, 2, 3, 4, 5, 6, 7);         \
  }
// all B frags (nj 0..1 x ks 0..1) from literal base BR: 8 ds_read_b128
#define RD_B(BR)                                                               \
  _Pragma("unroll") for (int nj = 0; nj < 2; ++nj) {                           \
    const char* p_ = lds + (BR) + nj * 4096;                                   \
    i32x4 lo0 = *(const i32x4*)(p_ + bL0);                                     \
    i32x4 hi0 = *(const i32x4*)(p_ + bH0);                                     \
    i32x4 lo1 = *(const i32x4*)(p_ + bL1);                                     \
    i32x4 hi1 = *(const i32x4*)(p_ + bH1);                                     \
    bf[nj][0] = __builtin_shufflevector(lo0, hi0, 0, 1, 2, 3, 4, 5, 6, 7);     \
    bf[nj][1] = __builtin_shufflevector(lo1, hi1, 0, 1, 2, 3, 4, 5, 6, 7);     \
  }

// ratio-fold + chained MFMA pair for one (mj,nj); acc touched only by the
// in-place mul and as MFMA C/D (R20-validated numerics).
#define MMFn(MJ, NJ, R_)                                                       \
  {                                                                            \
    _Pragma("unroll") for (int q = 0; q < 16; ++q)                             \
        acc[MJ][NJ][q] *= (R_);                                                \
    acc[MJ][NJ] = __builtin_amdgcn_mfma_scale_f32_32x32x64_f8f6f4(             \
        af[0], bf[NJ][0], acc[MJ][NJ], 0, 0, 0, 0x7f7f7f7f, 0, 0x7f7f7f7f);    \
    acc[MJ][NJ] = __builtin_amdgcn_mfma_scale_f32_32x32x64_f8f6f4(             \
        af[1], bf[NJ][1], acc[MJ][NJ], 0, 0, 0, 0x7f7f7f7f, 0, 0x7f7f7f7f);    \
  }

  // prologue: A(0)->A0, B(0)->B (6 gloads); drain; publish.
  STG_A(true, 0, pA);
  STG_B(true, 65536, pB);
  asm volatile("s_waitcnt vmcnt(0)" ::: "memory");
  __builtin_amdgcn_s_barrier();

  int rdA = 0, stA = 32768;    // A double-buffer swap
  const char* pAs = pA + 128;  // stage source col of tile T+1
  const char* pBs = pB + 128;
  float sp_ = wsv[0];          // previous-tile scale (ratio = 1 at t = 0)

// body T: stage A(T+1) at top (full-body cover); after first MFMA chunk all
// ds reads are retired in-wave (in-order lgkm); explicit lgkmcnt(0) +
// barrier makes that block-wide -> STG_B(T+1) into the single B buf is
// race-free; vmcnt(0)+barrier close (A:4+B:2 outstanding, read next body).
#define TILE(T, G)                                                             \
  {                                                                            \
    float sc_ = wsv[(T)];                                                      \
    float r_ = sp_ / sc_;                                                      \
    RD_B(65536);                                                               \
    RD_A(rdA, 0);                                                              \
    STG_A(G, stA, pAs);                                                        \
    __builtin_amdgcn_s_setprio(1);                                             \
    MMFn(0, 0, r_);                                                            \
    __builtin_amdgcn_s_setprio(0);                                             \
    asm volatile("s_waitcnt lgkmcnt(0)" ::: "memory");                         \
    __builtin_amdgcn_s_barrier();                                              \
    STG_B(G, 65536, pBs);                                                      \
    __builtin_amdgcn_s_setprio(1);                                             \
    MMFn(0, 1, r_);                                                            \
    __builtin_amdgcn_s_setprio(0);                                             \
    RD_A(rdA, 1);                                                              \
    __builtin_amdgcn_s_setprio(1);                                             \
    MMFn(1, 0, r_);                                                            \
    MMFn(1, 1, r_);                                                            \
    __builtin_amdgcn_s_setprio(0);                                             \
    sp_ = sc_;                                                                 \
    asm volatile("s_waitcnt vmcnt(0)" ::: "memory");                           \
    __builtin_amdgcn_s_barrier();                                              \
    rdA ^= 32768;                                                              \
    stA ^= 32768;                                                              \
    pAs += 128;                                                                \
    pBs += 128;                                                                \
  }

#pragma unroll 1
  for (int t = 0; t < KB - 1; ++t) {
    TILE(t, true)
  }
  // last tile: no staging.
  TILE(KB - 1, false)

#undef TILE
#undef MMFn
#undef RD_B
#undef RD_A
#undef STG_B
#undef STG_A
#undef GL

  // epilogue (validated C/D mapping): col=l31, row=q*8+hi2*4+j.
  // acc is in s_last domain: Y = acc * s_last * xs[row].
  const float sl_ = sp_;
#pragma unroll
  for (int mj = 0; mj < 2; ++mj)
#pragma unroll
    for (int nj = 0; nj < 2; ++nj) {
      int col = n0 + wc * 64 + nj * 32 + l31;
#pragma unroll
      for (int q = 0; q < 4; ++q) {
        int row0 = m0 + wr * 64 + mj * 32 + q * 8 + hi2 * 4;
        f32x4 sv = *(const f32x4*)(xs + row0);
#pragma unroll
        for (int j = 0; j < 4; ++j)
          Y[(size_t)(row0 + j) * N + col] = acc[mj][nj][q * 4 + j] * sv[j] * sl_;
      }
    }
}

// ---------------------------------------------------------------------------
extern "C" void kernel_launch(void* const* d_in, const int* in_sizes, int n_in,
                              void* d_out, int out_size, void* d_ws, size_t ws_size,
                              hipStream_t stream) {
  const float* x     = (const float*)d_in[0];   // [B,S,K] f32
  const float* w     = (const float*)d_in[1];   // [N,K] f32 (fp8-representable)
  const float* wsinv = (const float*)d_in[2];   // [N/128,K/128] f32
  float* y = (float*)d_out;

  const int K = 4096;
  const int M = in_sizes[0] / K;   // 4096
  const int N = in_sizes[1] / K;   // 8192

  unsigned char* x8 = (unsigned char*)d_ws;                       // M*K
  float* xs = (float*)((char*)d_ws + (size_t)M * K);              // M floats
  unsigned char* w8 =
      (unsigned char*)d_ws + (size_t)M * K + (size_t)M * 4;       // N*K

  quant_x_fp8_kernel<<<M, 256, 0, stream>>>(x, x8, xs, K);
  quant_w_fp8_kernel<<<(int)(((size_t)N * K / 16 + 255) / 256), 256, 0,
                       stream>>>(w, w8);

  dim3 grid((M / 256) * (N / 128));  // 1024
  gemm_mxfp8_kernel<<<grid, 512, 0, stream>>>(x8, w8, xs, wsinv, y, M, N, K);
}

// Round 11
// 219.598 us; speedup vs baseline: 3.7525x; 1.0878x over previous
//
#include <hip/hip_runtime.h>

typedef float f32x4  __attribute__((ext_vector_type(4)));
typedef float f32x16 __attribute__((ext_vector_type(16)));
typedef int   i32x4  __attribute__((ext_vector_type(4)));
typedef int   i32x8  __attribute__((ext_vector_type(8)));

#define AS1 __attribute__((address_space(1)))
#define AS3 __attribute__((address_space(3)))

// ---------------------------------------------------------------------------
// Kernel 1 (R1, proven): per-token quant of x -> fp8 e4m3 + scale
// ---------------------------------------------------------------------------
__global__ __launch_bounds__(256) void quant_x_fp8_kernel(
    const float* __restrict__ x, unsigned char* __restrict__ x8,
    float* __restrict__ xs, int K) {
  int m = blockIdx.x;
  int t = threadIdx.x;
  const f32x4* src = (const f32x4*)(x + (size_t)m * K + t * 16);
  f32x4 v[4];
  float am = 0.0f;
#pragma unroll
  for (int i = 0; i < 4; ++i) {
    v[i] = src[i];
#pragma unroll
    for (int j = 0; j < 4; ++j) am = fmaxf(am, __builtin_fabsf(v[i][j]));
  }
#pragma unroll
  for (int off = 32; off >= 1; off >>= 1)
    am = fmaxf(am, __shfl_xor(am, off, 64));
  __shared__ float red[4];
  int wv = t >> 6, lane = t & 63;
  if (lane == 0) red[wv] = am;
  __syncthreads();
  am = fmaxf(fmaxf(red[0], red[1]), fmaxf(red[2], red[3]));
  am = fmaxf(am, 1e-12f);
  float sc = am / 448.0f;
  if (t == 0) xs[m] = sc;
  i32x4 out;
#pragma unroll
  for (int i = 0; i < 4; ++i) {
    float q0 = v[i][0] / sc, q1 = v[i][1] / sc;
    float q2 = v[i][2] / sc, q3 = v[i][3] / sc;
    int p = __builtin_amdgcn_cvt_pk_fp8_f32(q0, q1, 0, false);
    p = __builtin_amdgcn_cvt_pk_fp8_f32(q2, q3, p, true);
    out[i] = p;
  }
  *(i32x4*)(x8 + (size_t)m * K + t * 16) = out;
}

// ---------------------------------------------------------------------------
// Kernel 2 (R1, proven): weight f32 (fp8-representable) -> fp8 bytes
// ---------------------------------------------------------------------------
__global__ __launch_bounds__(256) void quant_w_fp8_kernel(
    const float* __restrict__ w, unsigned char* __restrict__ w8) {
  size_t idx = (size_t)blockIdx.x * 256 + threadIdx.x;
  const f32x4* src = (const f32x4*)w + idx * 4;
  i32x4 out;
#pragma unroll
  for (int i = 0; i < 4; ++i) {
    f32x4 v = src[i];
    int p = __builtin_amdgcn_cvt_pk_fp8_f32(v[0], v[1], 0, false);
    p = __builtin_amdgcn_cvt_pk_fp8_f32(v[2], v[3], p, true);
    out[i] = p;
  }
  ((i32x4*)w8)[idx] = out;
}

// ---------------------------------------------------------------------------
// Kernel 3: MX-fp8 GEMM. R23 = 128x128 tile / 256 threads / 64KB LDS ->
// 2 independent blocks per CU.
// R22 post-mortem: exact-fit 80KB did NOT double-book (Occupancy stayed
// 22.7 -> 1 block/CU) and the mid-body lgkm+barrier cost 169->190us vs
// R20. Model (R17/R20/R22 invariant): ~3300cy/tile = LDS ~1920 + MFMA
// 1100 + VALU ~600 SERIAL inside phase-locked waves of one resident
// block; LDS term fixed by 64x64-wave-tile fragment duplication (VGPR
// wall). Only remaining lever: overlap via INDEPENDENT co-resident
// blocks -> LDS must be comfortably < 80KB.
// R23: 128(M)x128(N) tile, 256 thr, 4 waves 2(wr)x2(wc), wave 64x64
// (proven acc[2][2] f32x16 + fold + swizzle + C/D mapping unchanged).
// LDS = 2 bufs x {A 16KB, B 16KB} = 65536 -> 2 blocks/CU (128KB + 32KB
// slack). Schedule = R20-style: 1 barrier/tile; stage T+1 at body top
// into buf (T+1)&1 = buf(T-1) (last read 1 barrier earlier -> race-free);
// vmcnt(0) at body close (cover ~ full body > 900cy HBM).
// launch_bounds(256,2) -> allocator cap 256 >= measured ~96 body.
// Fold (R20-validated): acc *= s_prev/s_cur in place; MFMA C-chains;
// epilogue * s_last. Perfect-overlap floor: max(LDS 1920, MFMA 1100)
// per 8.4 MFLOP ~= 102us GEMM.
// Tripwires: Occupancy ~44 (22 => no co-residency); WRITE == 131072KB
// (else spill); VGPR ~96; LDS_Block 65536.
// ---------------------------------------------------------------------------
__global__ __launch_bounds__(256, 2) void gemm_mxfp8_kernel(
    const unsigned char* __restrict__ A8,   // [M][K] fp8
    const unsigned char* __restrict__ W8,   // [N][K] fp8
    const float* __restrict__ xs,           // [M]
    const float* __restrict__ wsinv,        // [N/128][K/128]
    float* __restrict__ Y,                  // [M][N] f32
    int M, int N, int K) {
  const int KB = K >> 7;  // K/128 tiles (32), even

  int bid = blockIdx.x, nwg = gridDim.x;
  int wg = (bid & 7) * (nwg >> 3) + (bid >> 3);
  int mt = M >> 7;                  // 32
  int bm = wg & (mt - 1);
  int bn = wg / mt;                 // 0..63
  int m0 = bm << 7, n0 = bn << 7;   // 128 x 128 tile

  __shared__ __align__(16) char lds[65536];  // buf0: A@0 B@16384; buf1: +32768

  const int tid = threadIdx.x, wv = tid >> 6, lane = tid & 63;
  const int wr = wv >> 1, wc = wv & 1;          // 2 x 2 wave grid
  const int l31 = lane & 31, hi2 = lane >> 5;
  const int salt = l31 & 7;

  // per-lane slot offsets (validated swizzle)
  const int sL0 = ((hi2 * 2 + 0) ^ salt) << 4;       // ks=0, k-low 16B
  const int sH0 = ((hi2 * 2 + 1) ^ salt) << 4;       // ks=0, k-high
  const int sL1 = ((4 + hi2 * 2 + 0) ^ salt) << 4;   // ks=1
  const int sH1 = ((4 + hi2 * 2 + 1) ^ salt) << 4;

  // per-lane anchors (buf base added as literal per body)
  const int aRow = (wr * 64 + l31) * 128;   // A row within 128-row panel
  const int bRow = (wc * 64 + l31) * 128;   // B row within 128-row panel
  const int aL0 = aRow + sL0, aH0 = aRow + sH0;
  const int aL1 = aRow + sL1, aH1 = aRow + sH1;
  const int bL0 = bRow + sL0, bH0 = bRow + sH0;
  const int bL1 = bRow + sL1, bH1 = bRow + sH1;

  // staging: 128-row panel (16KB) in 4 sweeps of 32 rows (256 thr x 16B);
  // dest = region + sweep*4096 + tid*16 (linear); source row = sweep*32 +
  // (tid>>3); col pre-swizzled (involution; row&7 == (tid>>3)&7).
  const int stgD = tid << 4;
  const int rIdx = tid >> 3;                 // 0..31
  const int cSrc = ((tid & 7) ^ ((tid >> 3) & 7)) << 4;
  const size_t rowB = (size_t)K;  // fp8: 1 byte/elem
  const size_t g32 = 32 * rowB;
  const char* pA = (const char*)A8 + (size_t)(m0 + rIdx) * rowB + cSrc;
  const char* pB = (const char*)W8 + (size_t)(n0 + rIdx) * rowB + cSrc;

  const float* wsv = wsinv + (size_t)bn * KB;  // one scale row per 128 cols

  f32x16 acc[2][2];
#pragma unroll
  for (int i = 0; i < 2; ++i)
#pragma unroll
    for (int j = 0; j < 2; ++j) acc[i][j] = (f32x16)0.0f;

  i32x8 af[2], bf[2][2];

#define GL(SRC, DST)                                                           \
  __builtin_amdgcn_global_load_lds((const AS1 void*)(SRC), (AS3 void*)(DST),   \
                                   16, 0, 0)
// one 128-row panel: 4 gloads (32-row sweeps)
#define STG(COND, SB, SRC)                                                     \
  if (COND) {                                                                  \
    const char* s_ = (SRC);                                                    \
    char* d_ = lds + (SB) + stgD;                                              \
    GL(s_, d_);                                                                \
    GL(s_ + g32, d_ + 4096);                                                   \
    GL(s_ + 2 * g32, d_ + 8192);                                               \
    GL(s_ + 3 * g32, d_ + 12288);                                              \
  }

// A frags for one mj (both ksteps), literal buf base RB: 4 ds_read_b128
#define RD_A(RB, MJ)                                                           \
  {                                                                            \
    const char* p_ = lds + (RB) + (MJ) * 4096;                                 \
    i32x4 lo0 = *(const i32x4*)(p_ + aL0);                                     \
    i32x4 hi0 = *(const i32x4*)(p_ + aH0);                                     \
    i32x4 lo1 = *(const i32x4*)(p_ + aL1);                                     \
    i32x4 hi1 = *(const i32x4*)(p_ + aH1);                                     \
    af[0] = __builtin_shufflevector(lo0, hi0, 0, 1, 2, 3, 4, 5, 6, 7);         \
    af[1] = __builtin_shufflevector(lo1, hi1, 0, 1, 2, 3, 4, 5, 6, 7);         \
  }
// all B frags (nj 0..1 x ks 0..1), literal buf base RB (B region +16384)
#define RD_B(RB)                                                               \
  _Pragma("unroll") for (int nj = 0; nj < 2; ++nj) {                           \
    const char* p_ = lds + (RB) + 16384 + nj * 4096;                           \
    i32x4 lo0 = *(const i32x4*)(p_ + bL0);                                     \
    i32x4 hi0 = *(const i32x4*)(p_ + bH0);                                     \
    i32x4 lo1 = *(const i32x4*)(p_ + bL1);                                     \
    i32x4 hi1 = *(const i32x4*)(p_ + bH1);                                     \
    bf[nj][0] = __builtin_shufflevector(lo0, hi0, 0, 1, 2, 3, 4, 5, 6, 7);     \
    bf[nj][1] = __builtin_shufflevector(lo1, hi1, 0, 1, 2, 3, 4, 5, 6, 7);     \
  }

// ratio-fold + chained MFMA pair for one (mj,nj); acc touched only by the
// in-place mul and as MFMA C/D (R20-validated numerics).
#define MMFn(MJ, NJ, R_)                                                       \
  {                                                                            \
    _Pragma("unroll") for (int q = 0; q < 16; ++q)                             \
        acc[MJ][NJ][q] *= (R_);                                                \
    acc[MJ][NJ] = __builtin_amdgcn_mfma_scale_f32_32x32x64_f8f6f4(             \
        af[0], bf[NJ][0], acc[MJ][NJ], 0, 0, 0, 0x7f7f7f7f, 0, 0x7f7f7f7f);    \
    acc[MJ][NJ] = __builtin_amdgcn_mfma_scale_f32_32x32x64_f8f6f4(             \
        af[1], bf[NJ][1], acc[MJ][NJ], 0, 0, 0, 0x7f7f7f7f, 0, 0x7f7f7f7f);    \
  }

  // prologue: stage tile0 -> buf0 (8 gloads); drain; publish.
  STG(true, 0, pA);
  STG(true, 16384, pB);
  asm volatile("s_waitcnt vmcnt(0)" ::: "memory");
  __builtin_amdgcn_s_barrier();

  const char* pAs = pA + 128;  // stage source col of tile T+1
  const char* pBs = pB + 128;
  float sp_ = wsv[0];          // previous-tile scale (ratio = 1 at t = 0)

// body T: read tile T from RB, stage T+1 -> SB (= buf of T-1, reads ended
// 1 barrier ago), MFMA with fold, vmcnt(0)+barrier close.
#define TILE(T, RB, SB, G)                                                     \
  {                                                                            \
    float sc_ = wsv[(T)];                                                      \
    float r_ = sp_ / sc_;                                                      \
    RD_B(RB);                                                                  \
    RD_A(RB, 0);                                                               \
    STG(G, (SB), pAs);                                                         \
    STG(G, (SB) + 16384, pBs);                                                 \
    __builtin_amdgcn_s_setprio(1);                                             \
    MMFn(0, 0, r_);                                                            \
    MMFn(0, 1, r_);                                                            \
    __builtin_amdgcn_s_setprio(0);                                             \
    RD_A(RB, 1);                                                               \
    __builtin_amdgcn_s_setprio(1);                                             \
    MMFn(1, 0, r_);                                                            \
    MMFn(1, 1, r_);                                                            \
    __builtin_amdgcn_s_setprio(0);                                             \
    sp_ = sc_;                                                                 \
    asm volatile("s_waitcnt vmcnt(0)" ::: "memory");                           \
    __builtin_amdgcn_s_barrier();                                              \
    pAs += 128;                                                                \
    pBs += 128;                                                                \
  }

#pragma unroll 1
  for (int t = 0; t < KB; t += 2) {
    TILE(t, 0, 32768, true)
    TILE(t + 1, 32768, 0, (t + 2) < KB)
  }

#undef TILE
#undef MMFn
#undef RD_B
#undef RD_A
#undef STG
#undef GL

  // epilogue (validated C/D mapping): col=l31, row=q*8+hi2*4+j.
  // acc is in s_last domain: Y = acc * s_last * xs[row].
  const float sl_ = sp_;
#pragma unroll
  for (int mj = 0; mj < 2; ++mj)
#pragma unroll
    for (int nj = 0; nj < 2; ++nj) {
      int col = n0 + wc * 64 + nj * 32 + l31;
#pragma unroll
      for (int q = 0; q < 4; ++q) {
        int row0 = m0 + wr * 64 + mj * 32 + q * 8 + hi2 * 4;
        f32x4 sv = *(const f32x4*)(xs + row0);
#pragma unroll
        for (int j = 0; j < 4; ++j)
          Y[(size_t)(row0 + j) * N + col] = acc[mj][nj][q * 4 + j] * sv[j] * sl_;
      }
    }
}

// ---------------------------------------------------------------------------
extern "C" void kernel_launch(void* const* d_in, const int* in_sizes, int n_in,
                              void* d_out, int out_size, void* d_ws, size_t ws_size,
                              hipStream_t stream) {
  const float* x     = (const float*)d_in[0];   // [B,S,K] f32
  const float* w     = (const float*)d_in[1];   // [N,K] f32 (fp8-representable)
  const float* wsinv = (const float*)d_in[2];   // [N/128,K/128] f32
  float* y = (float*)d_out;

  const int K = 4096;
  const int M = in_sizes[0] / K;   // 4096
  const int N = in_sizes[1] / K;   // 8192

  unsigned char* x8 = (unsigned char*)d_ws;                       // M*K
  float* xs = (float*)((char*)d_ws + (size_t)M * K);              // M floats
  unsigned char* w8 =
      (unsigned char*)d_ws + (size_t)M * K + (size_t)M * 4;       // N*K

  quant_x_fp8_kernel<<<M, 256, 0, stream>>>(x, x8, xs, K);
  quant_w_fp8_kernel<<<(int)(((size_t)N * K / 16 + 255) / 256), 256, 0,
                       stream>>>(w, w8);

  dim3 grid((M / 128) * (N / 128));  // 2048
  gemm_mxfp8_kernel<<<grid, 256, 0, stream>>>(x8, w8, xs, wsinv, y, M, N, K);
}